// Round 7
// baseline (119.520 us; speedup 1.0000x reference)
//
#include <hip/hip_runtime.h>

// out[b][t][w] (f32x4) = x[b][(t + w - 15) mod T] (f32x4)
// B=128, T=16384, F=4, wow=16.
//
// Fill-pattern sweep: 8192 resident waves, 64 steps. At step s the WHOLE
// device writes one contiguous 8 MB span (out f32x4 index
// s*2^19 + g*64 + lane) — identical instantaneous footprint to the 6.7 TB/s
// memset kernel. Geometry gift: wave g's source rows t0-15..t0+3
// (t0 = 4g mod T) are constant across steps; only the batch advances (b =
// 2s + g>>12). Per step: 1 cache-hit load (19 lanes) + 4 shfl + 1 NT store.

typedef float f32x4 __attribute__((ext_vector_type(4)));

__global__ __launch_bounds__(256, 8) void ring_pad_kernel(
    const f32x4* __restrict__ x, f32x4* __restrict__ out) {
    constexpr int T     = 16384;
    constexpr int STEPS = 64;
    constexpr int XMASK = (1 << 21) - 1;   // x has 2^21 f32x4 rows

    int tid  = threadIdx.x;
    int lane = tid & 63;
    int g    = (((int)blockIdx.x << 8) + tid) >> 6;   // global wave id 0..8191

    int t0 = (g << 2) & (T - 1);       // first output t-row of this wave
    int hi = g >> 12;                  // batch low bit
    int j  = lane < 19 ? lane : 18;    // source-row slot held by this lane
    int w  = lane & 15;                // window slot
    int tl = (lane >> 4) & 3;          // row-within-quad
    int src = tl + w;                  // shfl source lane, 0..18

    // x f32x4 index for this lane at step 0; advances by 2 batches (1<<15)
    // per step; AND keeps the one wasted final prefetch in bounds.
    int idx = (hi << 14) + ((t0 + T - 15 + j) & (T - 1));

    f32x4* op = out + ((size_t)g << 6) + lane;   // advances 8 MB (1<<19) per step

    f32x4 r = x[idx];
    idx = (idx + (1 << 15)) & XMASK;

    #pragma unroll 4
    for (int s = 0; s < STEPS; ++s) {
        f32x4 rn = x[idx];                       // prefetch next step's rows
        idx = (idx + (1 << 15)) & XMASK;

        f32x4 v;
        v[0] = __shfl(r[0], src, 64);
        v[1] = __shfl(r[1], src, 64);
        v[2] = __shfl(r[2], src, 64);
        v[3] = __shfl(r[3], src, 64);
        __builtin_nontemporal_store(v, op);
        op += (1 << 19);
        r = rn;
    }
}

extern "C" void kernel_launch(void* const* d_in, const int* in_sizes, int n_in,
                              void* d_out, int out_size, void* d_ws, size_t ws_size,
                              hipStream_t stream) {
    const f32x4* x = (const f32x4*)d_in[0];   // (128, 16384, 4) fp32
    f32x4* out = (f32x4*)d_out;               // (128, 16384, 64) fp32

    ring_pad_kernel<<<2048, 256, 0, stream>>>(x, out);
}

// Round 8
// 101.238 us; speedup vs baseline: 1.1806x; 1.1806x over previous
//
#include <hip/hip_runtime.h>

// out[b][t][w] (f32x4) = x[b][(t + w - 15) mod T] (f32x4)
// B=128, T=16384, F=4, wow=16.
//
// Wave-sequential sweep: 8192 resident waves, each owning one contiguous
// 64 KB output region written as 16 iterations x 4 KB (64 sequential 1 KB NT
// stores) — maximal per-wave DRAM row locality. Per iteration: lanes 0..30
// load the 31 needed x rows (cache-hit), __shfl distributes, 4 NT stores.
// No LDS, no barriers. (Run-length ladder: 1KB runs -> 112-122us,
// 4KB runs -> 101us, this tests 64KB runs.)

typedef float f32x4 __attribute__((ext_vector_type(4)));

__global__ __launch_bounds__(256, 8) void ring_pad_kernel(
    const f32x4* __restrict__ x, f32x4* __restrict__ out) {
    constexpr int T    = 16384;
    constexpr int ITER = 16;

    int lane = threadIdx.x & 63;
    int g    = (((int)blockIdx.x << 8) + threadIdx.x) >> 6;  // wave id 0..8191

    int w  = lane & 15;              // window slot
    int tl = (lane >> 4) & 3;        // row-within-quad
    int j  = lane < 31 ? lane : 30;  // source-row slot held by this lane

    #pragma unroll 2
    for (int m = 0; m < ITER; ++m) {
        int c  = g * ITER + m;       // 16-row chunk id: wave-sequential
        int b  = c >> 10;            // batch
        int R0 = (c & 1023) << 4;    // first output t-row of chunk

        // lane j holds x[b, (R0 - 15 + j) mod T]
        f32x4 r = x[((size_t)b << 14) + ((R0 - 15 + j) & (T - 1))];

        f32x4* ob = out + ((size_t)c << 8);
        #pragma unroll
        for (int s = 0; s < 4; ++s) {
            int src = s * 4 + tl + w;          // 0..30
            f32x4 v;
            v[0] = __shfl(r[0], src, 64);
            v[1] = __shfl(r[1], src, 64);
            v[2] = __shfl(r[2], src, 64);
            v[3] = __shfl(r[3], src, 64);
            __builtin_nontemporal_store(v, &ob[s * 64 + lane]);
        }
    }
}

extern "C" void kernel_launch(void* const* d_in, const int* in_sizes, int n_in,
                              void* d_out, int out_size, void* d_ws, size_t ws_size,
                              hipStream_t stream) {
    const f32x4* x = (const f32x4*)d_in[0];   // (128, 16384, 4) fp32
    f32x4* out = (f32x4*)d_out;               // (128, 16384, 64) fp32

    ring_pad_kernel<<<2048, 256, 0, stream>>>(x, out);
}